// Round 7
// baseline (1174.854 us; speedup 1.0000x reference)
//
#include <hip/hip_runtime.h>
#include <hip/hip_bf16.h>

typedef __hip_bfloat16 bf16;
typedef __attribute__((ext_vector_type(8))) short short8;   // 8 bf16 = 4 VGPRs
typedef __attribute__((ext_vector_type(4))) float f32x4;

#define NEGF (-3.402823466e38f)
#define SCALE 0.08838834764831845f  // 128^-0.5

constexpr int S_    = 1024;
constexpr int H_    = 32;
constexpr int KVH_  = 8;
constexpr int DH_   = 128;
constexpr int QKVN  = 6144;   // H*DH + 2*KVH*DH
constexpr int NC_   = 64;     // S/CB
constexpr int CD_   = 2048;   // CB*DH

__device__ __forceinline__ short f2bf(float x) {
    union { float f; unsigned u; } v; v.f = x;
    unsigned r = v.u + 0x7fffu + ((v.u >> 16) & 1u);   // round-to-nearest-even
    return (short)(r >> 16);
}
__device__ __forceinline__ float bf2f(short h) {
    union { float f; unsigned u; } v; v.u = ((unsigned)(unsigned short)h) << 16;
    return v.f;
}

// async global->LDS, 16B per lane; LDS dest = wave-uniform base + lane*16
#define GLOAD16(gp, lp) __builtin_amdgcn_global_load_lds( \
    (const __attribute__((address_space(1))) unsigned int*)(gp), \
    (__attribute__((address_space(3))) unsigned int*)(lp), 16, 0, 0)

// ---------------------------------------------------------------------------
// split_pair: fp32 -> (hi, lo) bf16 arrays. n % 8 == 0.
// ---------------------------------------------------------------------------
__global__ void split_pair(const float* __restrict__ src, short* __restrict__ h,
                           short* __restrict__ l, long n)
{
    long i = ((long)blockIdx.x * blockDim.x + threadIdx.x) * 8;
    if (i >= n) return;
    float4 a0 = *(const float4*)&src[i];
    float4 a1 = *(const float4*)&src[i + 4];
    float e[8] = {a0.x, a0.y, a0.z, a0.w, a1.x, a1.y, a1.z, a1.w};
    short8 hh, ll;
    #pragma unroll
    for (int j = 0; j < 8; ++j) {
        short hv = f2bf(e[j]); hh[j] = hv; ll[j] = f2bf(e[j] - bf2f(hv));
    }
    *(short8*)&h[i] = hh;
    *(short8*)&l[i] = ll;
}

// ---------------------------------------------------------------------------
// Wave-synchronous bf16x3 MFMA GEMM: ONE wave per block, 64x64 tile,
// 3-deep LDS pipeline (48KB), NO barriers. Per K-step: stage tile t+2 ->
// s_waitcnt vmcnt(32) (tile t's 16 loads done; t+1,t+2's 32 in flight;
// prefetch distance = 2 compute phases ~800cyc, covers L2/HBM latency) ->
// swizzled ds_read frags -> 48 MFMA under setprio(1).
//
// LDS kq-XOR swizzle (rule #21: dest linear for global_load_lds, so the
// per-lane GLOBAL source is permuted and the read applies the same XOR):
// phys slot p at byte row*64 + p*16 holds logical kq = p ^ ((row>>1)&3).
// Read banks become 2-way aliased (free, m136) instead of 8-way.
// C = A*B^T, A = Ah+Al, B = Bh+Bl; acc += Ah*Bh + Ah*Bl + Al*Bh.
// Requires M,N % 64 == 0, K % 32 == 0, k_len % 32 == 0.
// ---------------------------------------------------------------------------
__global__ __launch_bounds__(64)
void gemm_w64(const short* __restrict__ Ah, const short* __restrict__ Al,
              const short* __restrict__ Bh, const short* __restrict__ Bl,
              float* __restrict__ C, float* __restrict__ Cpart,
              const float* __restrict__ bias,
              int M, int N, int K, int ldc, int k_len, int act)
{
    __shared__ short LA[3][2][2048];   // [buf][hi/lo][64 rows x 32 k, swz]
    __shared__ short LB[3][2][2048];
    const int lane = threadIdx.x;
    const int qd = lane >> 4, l16 = lane & 15;
    const int bm = blockIdx.y * 64, bn = blockIdx.x * 64;
    const int kbeg = blockIdx.z * k_len;
    const int kend = (kbeg + k_len < K) ? (kbeg + k_len) : K;

    // staging: instr c covers rows c*16..+16; lane i -> row c*16+(i>>2),
    // phys slot i&3, which must hold logical kq = (i&3) ^ ((i>>3)&3).
    const int srow = lane >> 2;
    const int skq  = (lane & 3) ^ ((lane >> 3) & 3);
    const short* gAh = Ah + (size_t)(bm + srow) * K + skq * 8;
    const short* gAl = Al + (size_t)(bm + srow) * K + skq * 8;
    const short* gBh = Bh + (size_t)(bn + srow) * K + skq * 8;
    const short* gBl = Bl + (size_t)(bn + srow) * K + skq * 8;

    #define STAGE(buf, kk) do {                                         \
        _Pragma("unroll")                                               \
        for (int c = 0; c < 4; ++c) {                                   \
            size_t go = (size_t)c * 16 * K + (kk);                      \
            GLOAD16(gAh + go, &LA[buf][0][c * 512]);                    \
            GLOAD16(gAl + go, &LA[buf][1][c * 512]);                    \
            GLOAD16(gBh + go, &LB[buf][0][c * 512]);                    \
            GLOAD16(gBl + go, &LB[buf][1][c * 512]);                    \
        } } while (0)

    f32x4 zero = {0.f, 0.f, 0.f, 0.f};
    f32x4 acc[4][4];
    #pragma unroll
    for (int i = 0; i < 4; ++i)
        #pragma unroll
        for (int j = 0; j < 4; ++j) acc[i][j] = zero;

    // read-side swizzle: p = qd ^ ((row>>1)&3), row = t*16+l16 -> t-invariant
    const int pA = qd ^ ((l16 >> 1) & 3);

    STAGE(0, kbeg);                                  // tile 0 in flight
    if (kbeg + 32 < kend) STAGE(1, kbeg + 32);       // tile 1 in flight
    int bc = 0, b1 = 1, b2 = 2;
    for (int k0 = kbeg; k0 < kend; k0 += 32) {
        if (k0 + 64 < kend) {
            STAGE(b2, k0 + 64);                      // tile t+2 in flight
            asm volatile("s_waitcnt vmcnt(32)" ::: "memory");  // t done
        } else if (k0 + 32 < kend) {
            asm volatile("s_waitcnt vmcnt(16)" ::: "memory");  // t done
        } else {
            asm volatile("s_waitcnt vmcnt(0)" ::: "memory");
        }
        short8 fah[4], fal[4], fbh[4], fbl[4];
        #pragma unroll
        for (int t = 0; t < 4; ++t) {
            int off = t * 512 + l16 * 32 + pA * 8;   // shorts, swizzled
            fah[t] = *(const short8*)&LA[bc][0][off];
            fal[t] = *(const short8*)&LA[bc][1][off];
            fbh[t] = *(const short8*)&LB[bc][0][off];
            fbl[t] = *(const short8*)&LB[bc][1][off];
        }
        __builtin_amdgcn_s_setprio(1);
        #pragma unroll
        for (int t = 0; t < 4; ++t)
            #pragma unroll
            for (int u = 0; u < 4; ++u) {
                acc[t][u] = __builtin_amdgcn_mfma_f32_16x16x32_bf16(fah[t], fbh[u], acc[t][u], 0, 0, 0);
                acc[t][u] = __builtin_amdgcn_mfma_f32_16x16x32_bf16(fah[t], fbl[u], acc[t][u], 0, 0, 0);
                acc[t][u] = __builtin_amdgcn_mfma_f32_16x16x32_bf16(fal[t], fbh[u], acc[t][u], 0, 0, 0);
            }
        __builtin_amdgcn_s_setprio(0);
        int tmp = bc; bc = b1; b1 = b2; b2 = tmp;    // rotate buffers
    }
    #undef STAGE

    // epilogue: C/D layout col=lane&15, row=qd*4+reg (m89-verified)
    float* dst = Cpart ? (Cpart + (size_t)blockIdx.z * M * ldc) : C;
    #pragma unroll
    for (int t = 0; t < 4; ++t) {
        #pragma unroll
        for (int u = 0; u < 4; ++u) {
            int row0 = bm + t * 16 + qd * 4;
            int col  = bn + u * 16 + l16;
            #pragma unroll
            for (int r = 0; r < 4; ++r) {
                float v = acc[t][u][r];
                if (!Cpart) {
                    if (bias) v += bias[col];
                    if (act == 1) v = fmaxf(v, 0.f);
                    else if (act == 2) v = 1.f / (1.f + expf(-v));
                }
                dst[(size_t)(row0 + r) * ldc + col] = v;
            }
        }
    }
}

// ---------------------------------------------------------------------------
// Vector fallback GEMM (small N / split-K): 128x128 tile, 8x8 regs per lane.
// ---------------------------------------------------------------------------
__global__ __launch_bounds__(256)
void gemm128(const float* __restrict__ A, const float* __restrict__ B,
             float* __restrict__ C, float* __restrict__ Cpart,
             const float* __restrict__ bias,
             int M, int N, int K, int k_len, int act)
{
    __shared__ float As[16][132];
    __shared__ float Bs[16][132];
    const int tid  = threadIdx.x;
    const int wave = tid >> 6, lane = tid & 63;
    const int wr = wave >> 1, wc = wave & 1;
    const int ro = wr * 64 + (lane >> 3) * 8;
    const int co = wc * 64 + (lane & 7) * 8;
    const int bm = blockIdx.y * 128, bn = blockIdx.x * 128;
    const int z  = blockIdx.z;
    const int kbeg = z * k_len;
    const int lr = tid >> 2;
    const int kq = (tid & 3) * 4;

    float acc[8][8];
    #pragma unroll
    for (int i = 0; i < 8; ++i)
        #pragma unroll
        for (int j = 0; j < 8; ++j) acc[i][j] = 0.f;

    for (int k0 = kbeg; k0 < kbeg + k_len; k0 += 16) {
        #pragma unroll
        for (int h = 0; h < 2; ++h) {
            int r = lr + h * 64;
            float4 av = make_float4(0.f, 0.f, 0.f, 0.f);
            float4 bv = make_float4(0.f, 0.f, 0.f, 0.f);
            if (bm + r < M) av = *(const float4*)&A[(size_t)(bm + r) * K + k0 + kq];
            if (bn + r < N) bv = *(const float4*)&B[(size_t)(bn + r) * K + k0 + kq];
            As[kq + 0][r] = av.x; As[kq + 1][r] = av.y;
            As[kq + 2][r] = av.z; As[kq + 3][r] = av.w;
            Bs[kq + 0][r] = bv.x; Bs[kq + 1][r] = bv.y;
            Bs[kq + 2][r] = bv.z; Bs[kq + 3][r] = bv.w;
        }
        __syncthreads();
        #pragma unroll
        for (int kk = 0; kk < 16; ++kk) {
            float4 a0 = *(const float4*)&As[kk][ro];
            float4 a1 = *(const float4*)&As[kk][ro + 4];
            float4 b0 = *(const float4*)&Bs[kk][co];
            float4 b1 = *(const float4*)&Bs[kk][co + 4];
            float a[8] = {a0.x, a0.y, a0.z, a0.w, a1.x, a1.y, a1.z, a1.w};
            float b[8] = {b0.x, b0.y, b0.z, b0.w, b1.x, b1.y, b1.z, b1.w};
            #pragma unroll
            for (int i = 0; i < 8; ++i)
                #pragma unroll
                for (int j = 0; j < 8; ++j)
                    acc[i][j] += a[i] * b[j];
        }
        __syncthreads();
    }

    if (Cpart) {
        float* P = Cpart + (size_t)z * M * N;
        #pragma unroll
        for (int i = 0; i < 8; ++i) {
            int row = bm + ro + i;
            #pragma unroll
            for (int jq = 0; jq < 2; ++jq) {
                int col = bn + co + jq * 4;
                if (col < N) {
                    float4 v = make_float4(acc[i][jq * 4 + 0], acc[i][jq * 4 + 1],
                                           acc[i][jq * 4 + 2], acc[i][jq * 4 + 3]);
                    *(float4*)&P[(size_t)row * N + col] = v;
                }
            }
        }
    } else {
        #pragma unroll
        for (int i = 0; i < 8; ++i) {
            int row = bm + ro + i;
            #pragma unroll
            for (int jq = 0; jq < 2; ++jq) {
                int col = bn + co + jq * 4;
                if (col < N) {
                    float4 v = make_float4(acc[i][jq * 4 + 0], acc[i][jq * 4 + 1],
                                           acc[i][jq * 4 + 2], acc[i][jq * 4 + 3]);
                    if (bias) {
                        float4 bv = *(const float4*)&bias[col];
                        v.x += bv.x; v.y += bv.y; v.z += bv.z; v.w += bv.w;
                    }
                    if (act == 1) {
                        v.x = fmaxf(v.x, 0.f); v.y = fmaxf(v.y, 0.f);
                        v.z = fmaxf(v.z, 0.f); v.w = fmaxf(v.w, 0.f);
                    } else if (act == 2) {
                        v.x = 1.f / (1.f + expf(-v.x)); v.y = 1.f / (1.f + expf(-v.y));
                        v.z = 1.f / (1.f + expf(-v.z)); v.w = 1.f / (1.f + expf(-v.w));
                    }
                    *(float4*)&C[(size_t)row * N + col] = v;
                }
            }
        }
    }
}

// ---------------------------------------------------------------------------
// Split-K reduce: C = act( sum_z P[z] + bias ).
// If Chi != nullptr, writes bf16 hi/lo split instead of float C.
// C may alias P's slice 0 (thread i touches only index i).
// ---------------------------------------------------------------------------
__global__ void reduce_slices(const float* __restrict__ P, float* __restrict__ C,
                              short* __restrict__ Chi, short* __restrict__ Clo,
                              const float* __restrict__ bias,
                              int MN, int N, int KS, int act)
{
    int i4 = blockIdx.x * blockDim.x + threadIdx.x;
    size_t base = (size_t)i4 * 4;
    if (base >= (size_t)MN) return;
    float4 s = *(const float4*)&P[base];
    for (int z = 1; z < KS; ++z) {
        float4 v = *(const float4*)&P[(size_t)z * MN + base];
        s.x += v.x; s.y += v.y; s.z += v.z; s.w += v.w;
    }
    if (bias) {
        int col = (int)(base % N);
        float4 bv = *(const float4*)&bias[col];
        s.x += bv.x; s.y += bv.y; s.z += bv.z; s.w += bv.w;
    }
    if (act == 1) {
        s.x = fmaxf(s.x, 0.f); s.y = fmaxf(s.y, 0.f);
        s.z = fmaxf(s.z, 0.f); s.w = fmaxf(s.w, 0.f);
    } else if (act == 2) {
        s.x = 1.f / (1.f + expf(-s.x)); s.y = 1.f / (1.f + expf(-s.y));
        s.z = 1.f / (1.f + expf(-s.z)); s.w = 1.f / (1.f + expf(-s.w));
    }
    if (Chi) {
        float e[4] = {s.x, s.y, s.z, s.w};
        short4 hh, ll;
        hh.x = f2bf(e[0]); ll.x = f2bf(e[0] - bf2f(hh.x));
        hh.y = f2bf(e[1]); ll.y = f2bf(e[1] - bf2f(hh.y));
        hh.z = f2bf(e[2]); ll.z = f2bf(e[2] - bf2f(hh.z));
        hh.w = f2bf(e[3]); ll.w = f2bf(e[3] - bf2f(hh.w));
        *(short4*)&Chi[base] = hh;
        *(short4*)&Clo[base] = ll;
    } else {
        *(float4*)&C[base] = s;
    }
}

// ---------------------------------------------------------------------------
// build_cin: compress-branch input, fused fp32->bf16 hi/lo split.
// ---------------------------------------------------------------------------
__global__ void build_cin(const float* __restrict__ qkv,
                          const float* __restrict__ k_pos,
                          const float* __restrict__ v_pos,
                          short* __restrict__ ckh, short* __restrict__ ckl,
                          short* __restrict__ cvh, short* __restrict__ cvl)
{
    int idx = blockIdx.x * blockDim.x + threadIdx.x;       // KVH*S*DH
    if (idx >= KVH_ * S_ * DH_) return;
    int d = idx & 127;
    int s = (idx >> 7) & 1023;
    int h = idx >> 17;
    int c = s >> 4, t = s & 15;
    float kv = qkv[(size_t)s * QKVN + 4096 + h * DH_ + d];
    float vv = qkv[(size_t)s * QKVN + 5120 + h * DH_ + d];
    size_t row = (size_t)h * NC_ + c;
    size_t col = (size_t)t * DH_ + d;
    float kx = kv + k_pos[(h * 16 + t) * DH_ + d];
    float vx = vv + v_pos[(h * 16 + t) * DH_ + d];
    short kh = f2bf(kx), vh = f2bf(vx);
    ckh[row * CD_ + col] = kh; ckl[row * CD_ + col] = f2bf(kx - bf2f(kh));
    cvh[row * CD_ + col] = vh; cvl[row * CD_ + col] = f2bf(vx - bf2f(vh));
}

// ---------------------------------------------------------------------------
__global__ void assemble_c(const float* __restrict__ ckb, const float* __restrict__ cvb,
                           const float* __restrict__ mem_kv,
                           float* __restrict__ ckf, float* __restrict__ cvf)
{
    int idx = blockIdx.x * blockDim.x + threadIdx.x;       // KVH*65*DH
    if (idx >= KVH_ * 65 * DH_) return;
    int d = idx & 127;
    int j = (idx >> 7) % 65;
    int h = idx / (65 * DH_);
    if (j == 0) {
        ckf[idx] = mem_kv[(0 * KVH_ + h) * DH_ + d];
        cvf[idx] = mem_kv[(1 * KVH_ + h) * DH_ + d];
    } else {
        ckf[idx] = ckb[((size_t)h * NC_ + (j - 1)) * DH_ + d];
        cvf[idx] = cvb[((size_t)h * NC_ + (j - 1)) * DH_ + d];
    }
}

// ---------------------------------------------------------------------------
// Compressed attention, g4-batched: one block per (kvh, s), all 4 grouped
// q-heads share the K/V rows. Fused importance softmax + top-4 selection
// (runs on wave 1 via argmax shuffles) -> csim buffer eliminated.
// ---------------------------------------------------------------------------
__global__ void compress_attn(const float* __restrict__ qkv,
                              const float* __restrict__ ckf,
                              const float* __restrict__ cvf,
                              float* __restrict__ cout,
                              int* __restrict__ selidx, int* __restrict__ fsel)
{
    int b = blockIdx.x;            // h*1024 + s
    int s = b & 1023;
    int h = b >> 10;
    int tid = threadIdx.x;         // 128 = 2 waves
    int wv = tid >> 6;
    __shared__ __align__(16) float qrow[4][128];
    __shared__ float simS[4][65];
    __shared__ float p[4][128];
    __shared__ float redm[2][4], redd[2][4];
    #pragma unroll
    for (int g = 0; g < 4; ++g)
        qrow[g][tid] = qkv[(size_t)s * QKVN + (h * 4 + g) * DH_ + tid];
    __syncthreads();

    float sv[4] = {NEGF, NEGF, NEGF, NEGF};
    if (tid < 65) {
        bool vis = (tid == 0) || (16 * tid - 1 < s);
        if (vis) {
            const float4* kr = (const float4*)(ckf + ((size_t)h * 65 + tid) * DH_);
            float a[4] = {0.f, 0.f, 0.f, 0.f};
            #pragma unroll 4
            for (int d = 0; d < 32; ++d) {
                float4 kq = kr[d];
                #pragma unroll
                for (int g = 0; g < 4; ++g) {
                    float4 qq = *(const float4*)&qrow[g][d * 4];
                    a[g] += kq.x * qq.x + kq.y * qq.y + kq.z * qq.z + kq.w * qq.w;
                }
            }
            #pragma unroll
            for (int g = 0; g < 4; ++g) sv[g] = a[g] * SCALE;
        }
        #pragma unroll
        for (int g = 0; g < 4; ++g) simS[g][tid] = sv[g];
    }

    // wave-parallel softmax x4 (lanes >=65 hold NEGF -> e=0)
    float mg[4];
    #pragma unroll
    for (int g = 0; g < 4; ++g) mg[g] = sv[g];
    #pragma unroll
    for (int off = 32; off; off >>= 1)
        #pragma unroll
        for (int g = 0; g < 4; ++g) mg[g] = fmaxf(mg[g], __shfl_xor(mg[g], off));
    if ((tid & 63) == 0)
        #pragma unroll
        for (int g = 0; g < 4; ++g) redm[wv][g] = mg[g];
    __syncthreads();                    // also publishes simS
    float e[4];
    #pragma unroll
    for (int g = 0; g < 4; ++g) {
        float m = fmaxf(redm[0][g], redm[1][g]);
        e[g] = (tid < 65) ? expf(sv[g] - m) : 0.f;
        p[g][tid] = e[g];
    }
    __syncthreads();
    #pragma unroll
    for (int off = 32; off; off >>= 1)
        #pragma unroll
        for (int g = 0; g < 4; ++g) e[g] += __shfl_xor(e[g], off);
    if ((tid & 63) == 0)
        #pragma unroll
        for (int g = 0; g < 4; ++g) redd[wv][g] = e[g];
    __syncthreads();
    float inv[4];
    #pragma unroll
    for (int g = 0; g < 4; ++g) inv[g] = 1.f / (redd[0][g] + redd[1][g]);

    // importance + top-4 on wave 1 (lane j = key j+1); wave 0 goes to PV
    if (wv == 1) {
        int j = tid - 64;
        float v = 0.25f * (simS[0][j + 1] + simS[1][j + 1] +
                           simS[2][j + 1] + simS[3][j + 1]);
        float m2 = v;
        #pragma unroll
        for (int off = 32; off; off >>= 1) m2 = fmaxf(m2, __shfl_xor(m2, off));
        m2 = fmaxf(m2, -1e3f);
        float e2 = expf(v - m2);
        float den2 = e2;
        #pragma unroll
        for (int off = 32; off; off >>= 1) den2 += __shfl_xor(den2, off);
        den2 += expf(-1e3f - m2);
        float pv = e2 / den2;           // lane j holds prob of block j
        size_t base5 = ((size_t)h * S_ + s) * 5;
        size_t base4 = ((size_t)h * S_ + s) * 4;
        float cv = pv; int ci = j;
        for (int t = 0; t < 4; ++t) {
            float bv = cv; int bi = ci;
            #pragma unroll
            for (int off = 32; off; off >>= 1) {
                float ov = __shfl_xor(bv, off);
                int   oi = __shfl_xor(bi, off);
                if (ov > bv || (ov == bv && oi < bi)) { bv = ov; bi = oi; }
            }
            if (j == 0) {
                selidx[base5 + t] = bi;
                fsel[base4 + t]   = (bv > 1e-10f) ? 1 : 0;
            }
            if (ci == bi) cv = -1.f;    // remove winner
        }
        if (j == 0) selidx[base5 + 4] = s >> 4;
    }

    // PV: thread owns output dim d=tid for all 4 g
    float acc[4] = {0.f, 0.f, 0.f, 0.f};
    const float* vbase = cvf + (size_t)h * 65 * DH_ + tid;
    #pragma unroll 4
    for (int j = 0; j < 65; ++j) {
        float v = vbase[(size_t)j * DH_];
        #pragma unroll
        for (int g = 0; g < 4; ++g) acc[g] += p[g][j] * v;
    }
    #pragma unroll
    for (int g = 0; g < 4; ++g)
        cout[(size_t)s * 4096 + (h * 4 + g) * DH_ + tid] = acc[g] * inv[g];
}

// ---------------------------------------------------------------------------
__global__ void rope_inplace(float* __restrict__ qkv)
{
    int idx = blockIdx.x * blockDim.x + threadIdx.x;
    const int totq = S_ * H_ * 64;
    const int totk = S_ * KVH_ * 64;
    float* base;
    int p, s;
    if (idx < totq) {
        p = idx & 63; int head = (idx >> 6) & 31; s = idx >> 11;
        base = qkv + (size_t)s * QKVN + head * DH_;
    } else {
        int i2 = idx - totq;
        if (i2 >= totk) return;
        p = i2 & 63; int head = (i2 >> 6) & 7; s = i2 >> 9;
        base = qkv + (size_t)s * QKVN + 4096 + head * DH_;
    }
    // 10000^(-2p/128) = exp2(-p * log2(10000)/64)
    float inv = exp2f(-0.2076205060833595f * (float)p);
    float ang = (float)s * inv;
    float c = cosf(ang), sn = sinf(ang);
    float x0 = base[2 * p], x1 = base[2 * p + 1];
    base[2 * p]     = x0 * c - x1 * sn;
    base[2 * p + 1] = x1 * c + x0 * sn;
}

// ---------------------------------------------------------------------------
// Fine (selected-block) attention, g4-batched: one block per (kvh, s).
// 80 keys = 4 selected blocks + own block; 4 q-heads share K/V rows.
// ---------------------------------------------------------------------------
__global__ void fine_attn(const float* __restrict__ qkv,
                          const int* __restrict__ selidx, const int* __restrict__ fsel,
                          float* __restrict__ fout)
{
    int b = blockIdx.x;        // h*1024 + s
    int s = b & 1023;
    int h = b >> 10;
    int tid = threadIdx.x;     // 128 = 2 waves
    int wv = tid >> 6;
    __shared__ __align__(16) float qrow[4][128];
    __shared__ float p[4][128];
    __shared__ int   blk[5];
    __shared__ int   bvis[5];
    __shared__ float redm[2][4], redd[2][4];
    if (tid < 5) {
        blk[tid]  = selidx[((size_t)h * S_ + s) * 5 + tid];
        bvis[tid] = (tid < 4) ? fsel[((size_t)h * S_ + s) * 4 + tid] : 1;
    }
    #pragma unroll
    for (int g = 0; g < 4; ++g)
        qrow[g][tid] = qkv[(size_t)s * QKVN + (h * 4 + g) * DH_ + tid];
    __syncthreads();

    float sv[4] = {NEGF, NEGF, NEGF, NEGF};
    if (tid < 80) {
        int bi = tid >> 4, t = tid & 15;
        int pos = blk[bi] * 16 + t;
        bool vis = (bi < 4) ? (bvis[bi] != 0) : (t <= (s & 15));
        if (vis) {
            const float4* kr = (const float4*)(qkv + (size_t)pos * QKVN + 4096 + h * DH_);
            float a[4] = {0.f, 0.f, 0.f, 0.f};
            #pragma unroll 4
            for (int d = 0; d < 32; ++d) {
                float4 kq = kr[d];
                #pragma unroll
                for (int g = 0; g < 4; ++g) {
                    float4 qq = *(const float4*)&qrow[g][d * 4];
                    a[g] += kq.x * qq.x + kq.y * qq.y + kq.z * qq.z + kq.w * qq.w;
                }
            }
            #pragma unroll
            for (int g = 0; g < 4; ++g) sv[g] = a[g] * SCALE;
        }
    }

    float mg[4];
    #pragma unroll
    for (int g = 0; g < 4; ++g) mg[g] = sv[g];
    #pragma unroll
    for (int off = 32; off; off >>= 1)
        #pragma unroll
        for (int g = 0; g < 4; ++g) mg[g] = fmaxf(mg[g], __shfl_xor(mg[g], off));
    if ((tid & 63) == 0)
        #pragma unroll
        for (int g = 0; g < 4; ++g) redm[wv][g] = mg[g];
    __syncthreads();
    float e[4];
    #pragma unroll
    for (int g = 0; g < 4; ++g) {
        float m = fmaxf(redm[0][g], redm[1][g]);
        e[g] = (tid < 80) ? expf(sv[g] - m) : 0.f;
        p[g][tid] = e[g];
    }
    __syncthreads();
    #pragma unroll
    for (int off = 32; off; off >>= 1)
        #pragma unroll
        for (int g = 0; g < 4; ++g) e[g] += __shfl_xor(e[g], off);
    if ((tid & 63) == 0)
        #pragma unroll
        for (int g = 0; g < 4; ++g) redd[wv][g] = e[g];
    __syncthreads();
    float inv[4];
    #pragma unroll
    for (int g = 0; g < 4; ++g) inv[g] = 1.f / (redd[0][g] + redd[1][g]);

    float acc[4] = {0.f, 0.f, 0.f, 0.f};
    const float* vbase = qkv + 5120 + h * DH_ + tid;
    #pragma unroll
    for (int bi = 0; bi < 5; ++bi) {
        const float* vb = vbase + (size_t)(blk[bi] * 16) * QKVN;
        #pragma unroll 4
        for (int t = 0; t < 16; ++t) {
            float v = vb[(size_t)t * QKVN];
            #pragma unroll
            for (int g = 0; g < 4; ++g) acc[g] += p[g][bi * 16 + t] * v;
        }
    }
    #pragma unroll
    for (int g = 0; g < 4; ++g)
        fout[(size_t)s * 4096 + (h * 4 + g) * DH_ + tid] = acc[g] * inv[g];
}

// ---------------------------------------------------------------------------
// Sliding-window attention, g4-batched: one block per (kvh, s); 65 keys.
// ---------------------------------------------------------------------------
__global__ void sliding_attn(const float* __restrict__ qkv, float* __restrict__ sout)
{
    int b = blockIdx.x;        // kvh*1024 + s
    int s = b & 1023;
    int h = b >> 10;           // kvh
    int tid = threadIdx.x;     // 128 = 2 waves
    int wv = tid >> 6;
    __shared__ __align__(16) float qrow[4][128];
    __shared__ float p[4][128];
    __shared__ float redm[2][4], redd[2][4];
    #pragma unroll
    for (int g = 0; g < 4; ++g)
        qrow[g][tid] = qkv[(size_t)s * QKVN + (h * 4 + g) * DH_ + tid];
    __syncthreads();

    float sv[4] = {NEGF, NEGF, NEGF, NEGF};
    if (tid < 65) {
        int pos = s - tid;
        if (pos >= 0) {
            const float4* kr = (const float4*)(qkv + (size_t)pos * QKVN + 4096 + h * DH_);
            float a[4] = {0.f, 0.f, 0.f, 0.f};
            #pragma unroll 4
            for (int d = 0; d < 32; ++d) {
                float4 kq = kr[d];
                #pragma unroll
                for (int g = 0; g < 4; ++g) {
                    float4 qq = *(const float4*)&qrow[g][d * 4];
                    a[g] += kq.x * qq.x + kq.y * qq.y + kq.z * qq.z + kq.w * qq.w;
                }
            }
            #pragma unroll
            for (int g = 0; g < 4; ++g) sv[g] = a[g] * SCALE;
        }
    }

    float mg[4];
    #pragma unroll
    for (int g = 0; g < 4; ++g) mg[g] = sv[g];
    #pragma unroll
    for (int off = 32; off; off >>= 1)
        #pragma unroll
        for (int g = 0; g < 4; ++g) mg[g] = fmaxf(mg[g], __shfl_xor(mg[g], off));
    if ((tid & 63) == 0)
        #pragma unroll
        for (int g = 0; g < 4; ++g) redm[wv][g] = mg[g];
    __syncthreads();
    float e[4];
    #pragma unroll
    for (int g = 0; g < 4; ++g) {
        float m = fmaxf(redm[0][g], redm[1][g]);
        e[g] = (tid < 65) ? expf(sv[g] - m) : 0.f;
        p[g][tid] = e[g];
    }
    __syncthreads();
    #pragma unroll
    for (int off = 32; off; off >>= 1)
        #pragma unroll
        for (int g = 0; g < 4; ++g) e[g] += __shfl_xor(e[g], off);
    if ((tid & 63) == 0)
        #pragma unroll
        for (int g = 0; g < 4; ++g) redd[wv][g] = e[g];
    __syncthreads();
    float inv[4];
    #pragma unroll
    for (int g = 0; g < 4; ++g) inv[g] = 1.f / (redd[0][g] + redd[1][g]);

    float acc[4] = {0.f, 0.f, 0.f, 0.f};
    int lim = (s + 1 < 65) ? (s + 1) : 65;
    const float* vbase = qkv + (size_t)s * QKVN + 5120 + h * DH_ + tid;
    #pragma unroll 4
    for (int j = 0; j < lim; ++j) {
        float v = *(vbase - (size_t)j * QKVN);
        #pragma unroll
        for (int g = 0; g < 4; ++g) acc[g] += p[g][j] * v;
    }
    #pragma unroll
    for (int g = 0; g < 4; ++g)
        sout[(size_t)s * 4096 + (h * 4 + g) * DH_ + tid] = acc[g] * inv[g];
}

// ---------------------------------------------------------------------------
// combine_gate: gated 3-way sum, fused fp32->bf16 hi/lo split for out-proj A.
// ---------------------------------------------------------------------------
__global__ void combine_gate(const float* __restrict__ cout, const float* __restrict__ fout,
                             const float* __restrict__ sout, const float* __restrict__ gates,
                             short* __restrict__ oh, short* __restrict__ ol)
{
    int idx = blockIdx.x * blockDim.x + threadIdx.x;   // S*4096
    if (idx >= S_ * 4096) return;
    int h = (idx >> 7) & 31;
    int s = idx >> 12;
    float g0 = gates[(size_t)s * 96 + h * 3 + 0];
    float g1 = gates[(size_t)s * 96 + h * 3 + 1];
    float g2 = gates[(size_t)s * 96 + h * 3 + 2];
    float v = g0 * cout[idx] + g1 * fout[idx] + g2 * sout[idx];
    short hv = f2bf(v);
    oh[idx] = hv;
    ol[idx] = f2bf(v - bf2f(hv));
}

// ---------------------------------------------------------------------------
extern "C" void kernel_launch(void* const* d_in, const int* in_sizes, int n_in,
                              void* d_out, int out_size, void* d_ws, size_t ws_size,
                              hipStream_t stream)
{
    const float* hidden = (const float*)d_in[0];
    const float* w_qkv  = (const float*)d_in[1];
    const float* w_o    = (const float*)d_in[2];
    const float* k_pos  = (const float*)d_in[3];
    const float* v_pos  = (const float*)d_in[4];
    const float* k_w1   = (const float*)d_in[5];
    const float* k_b1   = (const float*)d_in[6];
    const float* k_w2   = (const float*)d_in[7];
    const float* k_b2   = (const float*)d_in[8];
    const float* v_w1   = (const float*)d_in[9];
    const float* v_b1   = (const float*)d_in[10];
    const float* v_w2   = (const float*)d_in[11];
    const float* v_b2   = (const float*)d_in[12];
    const float* mem_kv = (const float*)d_in[13];
    const float* w_gate = (const float*)d_in[14];
    const float* b_gate = (const float*)d_in[15];
    float* out = (float*)d_out;

    float* ws = (float*)d_ws;
    size_t o = 0;
    float* qkv    = ws + o; o += (size_t)S_ * QKVN;
    short* ckin_h = (short*)(ws + o); o += (size_t)512 * CD_ / 2;
    short* ckin_l = (short*)(ws + o); o += (size_t)512 * CD_ / 2;
    short* cvin_h = (short*)(ws + o); o += (size_t)512 * CD_ / 2;
    short* cvin_l = (short*)(ws + o); o += (size_t)512 * CD_ / 2;
    short* h1h    = (short*)(ws + o); o += (size_t)512 * CD_ / 2;
    short* h1l    = (short*)(ws + o); o += (size_t)512 * CD_ / 2;
    float* ckb    = ws + o; o += (size_t)512 * DH_;
    float* cvb    = ws + o; o += (size_t)512 * DH_;
    float* ckf    = ws + o; o += (size_t)KVH_ * 65 * DH_;
    float* cvf    = ws + o; o += (size_t)KVH_ * 65 * DH_;
    float* coutb  = ws + o; o += (size_t)S_ * 4096;
    float* foutb  = ws + o; o += (size_t)S_ * 4096;   // } pair doubles as
    float* soutb  = ws + o; o += (size_t)S_ * 4096;   // } split-K partials
    float* gatesb = ws + o; o += (size_t)S_ * 96;
    int*   selidx = (int*)(ws + o); o += (size_t)KVH_ * S_ * 5;
    int*   fsel   = (int*)(ws + o); o += (size_t)KVH_ * S_ * 4;
    short* hid_h  = (short*)(ws + o); o += (size_t)S_ * 4096 / 2;
    short* hid_l  = (short*)(ws + o); o += (size_t)S_ * 4096 / 2;
    short* cmb_h  = (short*)(ws + o); o += (size_t)S_ * 4096 / 2;
    short* cmb_l  = (short*)(ws + o); o += (size_t)S_ * 4096 / 2;
    // shared weight-split scratch, sized for w_qkv (largest); reused
    // sequentially (stream-ordered): w_qkv, k_w1, k_w2, v_w1, v_w2, w_o.
    short* wsp_h  = (short*)(ws + o); o += (size_t)QKVN * 4096 / 2;
    short* wsp_l  = (short*)(ws + o); o += (size_t)QKVN * 4096 / 2;

    // split-K partials for MLP1 (z=4, 4M floats), MLP2 (z=16, 1M), gates
    // (16 x 98K): foutb..soutb span, dead until step 12.
    float* P = foutb;

    // 0. pre-split activations/weights to bf16 hi/lo
    {
        long n = (long)S_ * 4096;
        split_pair<<<(int)((n / 8 + 255) / 256), 256, 0, stream>>>(hidden, hid_h, hid_l, n);
        long nw = (long)QKVN * 4096;
        split_pair<<<(int)((nw / 8 + 255) / 256), 256, 0, stream>>>(w_qkv, wsp_h, wsp_l, nw);
    }

    // 1. qkv projection [1024,6144] — wave-sync bf16x3 MFMA, direct write
    gemm_w64<<<dim3(QKVN / 64, S_ / 64, 1), 64, 0, stream>>>(
        hid_h, hid_l, wsp_h, wsp_l, qkv, nullptr, nullptr,
        S_, QKVN, 4096, QKVN, 4096, 0);

    // 2. gates [1024,96] — vector split-K=16 (N not a multiple of 64)
    gemm128<<<dim3(1, S_ / 128, 16), 256, 0, stream>>>(
        hidden, w_gate, nullptr, P, nullptr, S_, 96, 4096, 256, 0);
    reduce_slices<<<(S_ * 96 / 4 + 255) / 256, 256, 0, stream>>>(
        P, gatesb, nullptr, nullptr, b_gate, S_ * 96, 96, 16, 2);

    // 3. compress inputs (fused split)
    build_cin<<<(KVH_ * S_ * DH_ + 255) / 256, 256, 0, stream>>>(
        qkv, k_pos, v_pos, ckin_h, ckin_l, cvin_h, cvin_l);

    // 4-7. compress MLPs, all on the MFMA path.
    //      MLP1: z=4 (1024 blocks); reduce fuses relu + hi/lo split -> h1.
    //      MLP2: z=16 (256 blocks); reduce adds bias -> ckb/cvb fp32.
    {
        long nw = (long)CD_ * CD_;
        split_pair<<<(int)((nw / 8 + 255) / 256), 256, 0, stream>>>(k_w1, wsp_h, wsp_l, nw);
    }
    gemm_w64<<<dim3(CD_ / 64, 8, 4), 64, 0, stream>>>(
        ckin_h, ckin_l, wsp_h, wsp_l, nullptr, P, nullptr,
        512, CD_, CD_, CD_, 512, 0);
    reduce_slices<<<(512 * CD_ / 4 + 255) / 256, 256, 0, stream>>>(
        P, nullptr, h1h, h1l, k_b1, 512 * CD_, CD_, 4, 1);
    {
        long nw = (long)DH_ * CD_;
        split_pair<<<(int)((nw / 8 + 255) / 256), 256, 0, stream>>>(k_w2, wsp_h, wsp_l, nw);
    }
    gemm_w64<<<dim3(DH_ / 64, 8, 16), 64, 0, stream>>>(
        h1h, h1l, wsp_h, wsp_l, nullptr, P, nullptr,
        512, DH_, CD_, DH_, 128, 0);
    reduce_slices<<<(512 * DH_ / 4 + 255) / 256, 256, 0, stream>>>(
        P, ckb, nullptr, nullptr, k_b2, 512 * DH_, DH_, 16, 0);

    {
        long nw = (long)CD_ * CD_;
        split_pair<<<(int)((nw / 8 + 255) / 256), 256, 0, stream>>>(v_w1, wsp_h, wsp_l, nw);
    }
    gemm_w64<<<dim3(CD_ / 64, 8, 4), 64, 0, stream>>>(
        cvin_h, cvin_l, wsp_h, wsp_l, nullptr, P, nullptr,
        512, CD_, CD_, CD_, 512, 0);
    reduce_slices<<<(512 * CD_ / 4 + 255) / 256, 256, 0, stream>>>(
        P, nullptr, h1h, h1l, v_b1, 512 * CD_, CD_, 4, 1);
    {
        long nw = (long)DH_ * CD_;
        split_pair<<<(int)((nw / 8 + 255) / 256), 256, 0, stream>>>(v_w2, wsp_h, wsp_l, nw);
    }
    gemm_w64<<<dim3(DH_ / 64, 8, 16), 64, 0, stream>>>(
        h1h, h1l, wsp_h, wsp_l, nullptr, P, nullptr,
        512, DH_, CD_, DH_, 128, 0);
    reduce_slices<<<(512 * DH_ / 4 + 255) / 256, 256, 0, stream>>>(
        P, cvb, nullptr, nullptr, v_b2, 512 * DH_, DH_, 16, 0);

    // 8. prepend mem token
    assemble_c<<<(KVH_ * 65 * DH_ + 255) / 256, 256, 0, stream>>>(ckb, cvb, mem_kv, ckf, cvf);

    // 9+10. compressed attention, g4-batched + fused importance/top-k
    compress_attn<<<KVH_ * S_, 128, 0, stream>>>(qkv, ckf, cvf, coutb, selidx, fsel);

    // 11. RoPE in place on q and k slices of qkv
    {
        int tot = S_ * H_ * 64 + S_ * KVH_ * 64;
        rope_inplace<<<(tot + 255) / 256, 256, 0, stream>>>(qkv);
    }

    // 12. fine (selected-block) attention, g4-batched
    fine_attn<<<KVH_ * S_, 128, 0, stream>>>(qkv, selidx, fsel, foutb);

    // 13. sliding-window attention, g4-batched
    sliding_attn<<<KVH_ * S_, 128, 0, stream>>>(qkv, soutb);

    // 14. gated combine -> bf16 hi/lo (out-proj A operand)
    combine_gate<<<(S_ * 4096 + 255) / 256, 256, 0, stream>>>(
        coutb, foutb, soutb, gatesb, cmb_h, cmb_l);

    // 15. output projection [1024,4096] — wave-sync bf16x3 MFMA, direct
    {
        long nw = (long)4096 * 4096;
        split_pair<<<(int)((nw / 8 + 255) / 256), 256, 0, stream>>>(w_o, wsp_h, wsp_l, nw);
    }
    gemm_w64<<<dim3(4096 / 64, S_ / 64, 1), 64, 0, stream>>>(
        cmb_h, cmb_l, wsp_h, wsp_l, out, nullptr, nullptr,
        S_, 4096, 4096, 4096, 4096, 0);
}

// Round 8
// 1051.453 us; speedup vs baseline: 1.1174x; 1.1174x over previous
//
#include <hip/hip_runtime.h>
#include <hip/hip_bf16.h>

typedef __hip_bfloat16 bf16;
typedef __attribute__((ext_vector_type(8))) short short8;   // 8 bf16 = 4 VGPRs
typedef __attribute__((ext_vector_type(4))) float f32x4;

#define NEGF (-3.402823466e38f)
#define SCALE 0.08838834764831845f  // 128^-0.5

constexpr int S_    = 1024;
constexpr int H_    = 32;
constexpr int KVH_  = 8;
constexpr int DH_   = 128;
constexpr int QKVN  = 6144;   // H*DH + 2*KVH*DH
constexpr int NC_   = 64;     // S/CB
constexpr int CD_   = 2048;   // CB*DH

__device__ __forceinline__ short f2bf(float x) {
    union { float f; unsigned u; } v; v.f = x;
    unsigned r = v.u + 0x7fffu + ((v.u >> 16) & 1u);   // round-to-nearest-even
    return (short)(r >> 16);
}
__device__ __forceinline__ float bf2f(short h) {
    union { float f; unsigned u; } v; v.u = ((unsigned)(unsigned short)h) << 16;
    return v.f;
}

// async global->LDS, 16B per lane; LDS dest = wave-uniform base + lane*16
#define GLOAD16(gp, lp) __builtin_amdgcn_global_load_lds( \
    (const __attribute__((address_space(1))) unsigned int*)(gp), \
    (__attribute__((address_space(3))) unsigned int*)(lp), 16, 0, 0)

// ---------------------------------------------------------------------------
// split_pair: fp32 -> (hi, lo) bf16 arrays. n % 8 == 0.
// ---------------------------------------------------------------------------
__global__ void split_pair(const float* __restrict__ src, short* __restrict__ h,
                           short* __restrict__ l, long n)
{
    long i = ((long)blockIdx.x * blockDim.x + threadIdx.x) * 8;
    if (i >= n) return;
    float4 a0 = *(const float4*)&src[i];
    float4 a1 = *(const float4*)&src[i + 4];
    float e[8] = {a0.x, a0.y, a0.z, a0.w, a1.x, a1.y, a1.z, a1.w};
    short8 hh, ll;
    #pragma unroll
    for (int j = 0; j < 8; ++j) {
        short hv = f2bf(e[j]); hh[j] = hv; ll[j] = f2bf(e[j] - bf2f(hv));
    }
    *(short8*)&h[i] = hh;
    *(short8*)&l[i] = ll;
}

// ---------------------------------------------------------------------------
// Pure-bf16 x3 MFMA GEMM, single-buffer m97 structure (2-barrier K-loop),
// 4 waves, 128x128 tile. MEASURED BEST for the big GEMMs (R4: 238us qkv at
// z=2). Latency hiding via 3-4 co-resident blocks/CU (m114 implicit
// overlap) — grids grown via split-K. kend clamp allows uneven last chunk.
// C = A*B^T, A = Ah+Al, B = Bh+Bl; acc += Ah*Bh + Ah*Bl + Al*Bh.
// Requires M,N % 128 == 0, K % 32 == 0, k_len % 32 == 0.
// ---------------------------------------------------------------------------
__global__ __launch_bounds__(256)
void gemm_bf3(const short* __restrict__ Ah, const short* __restrict__ Al,
              const short* __restrict__ Bh, const short* __restrict__ Bl,
              float* __restrict__ C, float* __restrict__ Cpart,
              const float* __restrict__ bias,
              int M, int N, int K, int ldc, int k_len, int act)
{
    __shared__ short LAh[4096];
    __shared__ short LAl[4096];
    __shared__ short LBh[4096];
    __shared__ short LBl[4096];
    const int tid  = threadIdx.x;
    const int lane = tid & 63, wave = tid >> 6;
    const int wr = wave >> 1, wc = wave & 1;
    const int qd = lane >> 4, l16 = lane & 15;
    const int bm = blockIdx.y * 128, bn = blockIdx.x * 128;
    const int kbeg = blockIdx.z * k_len;
    const int kend = (kbeg + k_len < K) ? (kbeg + k_len) : K;

    // staging map: wave covers chunks c=0,1 -> cells (wave*2+c)*64 + lane
    const short* gA[2][2];   // [c][hi/lo]
    const short* gB[2][2];
    int cbase[2];
    #pragma unroll
    for (int c = 0; c < 2; ++c) {
        int cell = (wave * 2 + c) * 64 + lane;
        int row = cell & 127, kq = cell >> 7;
        size_t oa = (size_t)(bm + row) * K + kq * 8;
        size_t ob = (size_t)(bn + row) * K + kq * 8;
        gA[c][0] = Ah + oa; gA[c][1] = Al + oa;
        gB[c][0] = Bh + ob; gB[c][1] = Bl + ob;
        cbase[c] = (wave * 2 + c) * 512;   // shorts
    }

    f32x4 zero = {0.f, 0.f, 0.f, 0.f};
    f32x4 acc[4][4];
    #pragma unroll
    for (int i = 0; i < 4; ++i)
        #pragma unroll
        for (int j = 0; j < 4; ++j) acc[i][j] = zero;

    for (int k0 = kbeg; k0 < kend; k0 += 32) {
        #pragma unroll
        for (int c = 0; c < 2; ++c) {
            GLOAD16(gA[c][0] + k0, &LAh[cbase[c]]);
            GLOAD16(gA[c][1] + k0, &LAl[cbase[c]]);
            GLOAD16(gB[c][0] + k0, &LBh[cbase[c]]);
            GLOAD16(gB[c][1] + k0, &LBl[cbase[c]]);
        }
        __syncthreads();   // drains vmcnt; cross-block overlap hides the stall

        short8 fah[4], fal[4], fbh[4], fbl[4];
        #pragma unroll
        for (int t = 0; t < 4; ++t) {
            int ca = (qd * 128 + wr * 64 + t * 16 + l16) * 8;
            int cb = (qd * 128 + wc * 64 + t * 16 + l16) * 8;
            fah[t] = *(const short8*)&LAh[ca]; fal[t] = *(const short8*)&LAl[ca];
            fbh[t] = *(const short8*)&LBh[cb]; fbl[t] = *(const short8*)&LBl[cb];
        }
        #pragma unroll
        for (int i = 0; i < 4; ++i)
            #pragma unroll
            for (int j = 0; j < 4; ++j) {
                acc[i][j] = __builtin_amdgcn_mfma_f32_16x16x32_bf16(fah[i], fbh[j], acc[i][j], 0, 0, 0);
                acc[i][j] = __builtin_amdgcn_mfma_f32_16x16x32_bf16(fah[i], fbl[j], acc[i][j], 0, 0, 0);
                acc[i][j] = __builtin_amdgcn_mfma_f32_16x16x32_bf16(fal[i], fbh[j], acc[i][j], 0, 0, 0);
            }
        __syncthreads();
    }

    // epilogue: C/D layout col=lane&15, row=qd*4+reg (m89-verified)
    float* dst = Cpart ? (Cpart + (size_t)blockIdx.z * M * ldc) : C;
    #pragma unroll
    for (int i = 0; i < 4; ++i) {
        #pragma unroll
        for (int j = 0; j < 4; ++j) {
            int row0 = bm + wr * 64 + i * 16 + qd * 4;
            int col  = bn + wc * 64 + j * 16 + l16;
            #pragma unroll
            for (int r = 0; r < 4; ++r) {
                float v = acc[i][j][r];
                if (!Cpart) {
                    if (bias) v += bias[col];
                    if (act == 1) v = fmaxf(v, 0.f);
                    else if (act == 2) v = 1.f / (1.f + expf(-v));
                }
                dst[(size_t)(row0 + r) * ldc + col] = v;
            }
        }
    }
}

// ---------------------------------------------------------------------------
// Wave-synchronous bf16x3 MFMA GEMM (small-GEMM path only): ONE wave per
// block, 64x64 tile, 2-deep 32KB LDS pipeline (5 waves/CU), kq-XOR swizzle
// (R7-verified: bank conflicts -> 0), no barriers.
// ---------------------------------------------------------------------------
__global__ __launch_bounds__(64)
void gemm_w64(const short* __restrict__ Ah, const short* __restrict__ Al,
              const short* __restrict__ Bh, const short* __restrict__ Bl,
              float* __restrict__ C, float* __restrict__ Cpart,
              const float* __restrict__ bias,
              int M, int N, int K, int ldc, int k_len, int act)
{
    __shared__ short LA[2][2][2048];   // [buf][hi/lo][64 rows x 32 k, swz]
    __shared__ short LB[2][2][2048];
    const int lane = threadIdx.x;
    const int qd = lane >> 4, l16 = lane & 15;
    const int bm = blockIdx.y * 64, bn = blockIdx.x * 64;
    const int kbeg = blockIdx.z * k_len;
    const int kend = (kbeg + k_len < K) ? (kbeg + k_len) : K;

    // staging: instr c covers rows c*16..+16; lane i -> row c*16+(i>>2),
    // phys slot i&3 holds logical kq = (i&3) ^ ((i>>3)&3)  (rule #21:
    // linear LDS dest, permuted GLOBAL source, same XOR on read).
    const int srow = lane >> 2;
    const int skq  = (lane & 3) ^ ((lane >> 3) & 3);
    const short* gAh = Ah + (size_t)(bm + srow) * K + skq * 8;
    const short* gAl = Al + (size_t)(bm + srow) * K + skq * 8;
    const short* gBh = Bh + (size_t)(bn + srow) * K + skq * 8;
    const short* gBl = Bl + (size_t)(bn + srow) * K + skq * 8;

    #define STAGE(buf, kk) do {                                         \
        _Pragma("unroll")                                               \
        for (int c = 0; c < 4; ++c) {                                   \
            size_t go = (size_t)c * 16 * K + (kk);                      \
            GLOAD16(gAh + go, &LA[buf][0][c * 512]);                    \
            GLOAD16(gAl + go, &LA[buf][1][c * 512]);                    \
            GLOAD16(gBh + go, &LB[buf][0][c * 512]);                    \
            GLOAD16(gBl + go, &LB[buf][1][c * 512]);                    \
        } } while (0)

    f32x4 zero = {0.f, 0.f, 0.f, 0.f};
    f32x4 acc[4][4];
    #pragma unroll
    for (int i = 0; i < 4; ++i)
        #pragma unroll
        for (int j = 0; j < 4; ++j) acc[i][j] = zero;

    // read-side swizzle: p = qd ^ ((row>>1)&3), row = t*16+l16 -> t-invariant
    const int pA = qd ^ ((l16 >> 1) & 3);

    STAGE(0, kbeg);                 // prologue: tile 0 in flight
    int cur = 0;
    for (int k0 = kbeg; k0 < kend; k0 += 32) {
        if (k0 + 32 < kend) {
            STAGE(cur ^ 1, k0 + 32);
            asm volatile("s_waitcnt vmcnt(16)" ::: "memory");  // cur done
        } else {
            asm volatile("s_waitcnt vmcnt(0)" ::: "memory");
        }
        short8 fah[4], fal[4], fbh[4], fbl[4];
        #pragma unroll
        for (int t = 0; t < 4; ++t) {
            int off = t * 512 + l16 * 32 + pA * 8;   // shorts, swizzled
            fah[t] = *(const short8*)&LA[cur][0][off];
            fal[t] = *(const short8*)&LA[cur][1][off];
            fbh[t] = *(const short8*)&LB[cur][0][off];
            fbl[t] = *(const short8*)&LB[cur][1][off];
        }
        __builtin_amdgcn_s_setprio(1);
        #pragma unroll
        for (int t = 0; t < 4; ++t)
            #pragma unroll
            for (int u = 0; u < 4; ++u) {
                acc[t][u] = __builtin_amdgcn_mfma_f32_16x16x32_bf16(fah[t], fbh[u], acc[t][u], 0, 0, 0);
                acc[t][u] = __builtin_amdgcn_mfma_f32_16x16x32_bf16(fah[t], fbl[u], acc[t][u], 0, 0, 0);
                acc[t][u] = __builtin_amdgcn_mfma_f32_16x16x32_bf16(fal[t], fbh[u], acc[t][u], 0, 0, 0);
            }
        __builtin_amdgcn_s_setprio(0);
        cur ^= 1;
    }
    #undef STAGE

    // epilogue: C/D layout col=lane&15, row=qd*4+reg (m89-verified)
    float* dst = Cpart ? (Cpart + (size_t)blockIdx.z * M * ldc) : C;
    #pragma unroll
    for (int t = 0; t < 4; ++t) {
        #pragma unroll
        for (int u = 0; u < 4; ++u) {
            int row0 = bm + t * 16 + qd * 4;
            int col  = bn + u * 16 + l16;
            #pragma unroll
            for (int r = 0; r < 4; ++r) {
                float v = acc[t][u][r];
                if (!Cpart) {
                    if (bias) v += bias[col];
                    if (act == 1) v = fmaxf(v, 0.f);
                    else if (act == 2) v = 1.f / (1.f + expf(-v));
                }
                dst[(size_t)(row0 + r) * ldc + col] = v;
            }
        }
    }
}

// ---------------------------------------------------------------------------
// Vector fallback GEMM (small N / split-K): 128x128 tile, 8x8 regs per lane.
// ---------------------------------------------------------------------------
__global__ __launch_bounds__(256)
void gemm128(const float* __restrict__ A, const float* __restrict__ B,
             float* __restrict__ C, float* __restrict__ Cpart,
             const float* __restrict__ bias,
             int M, int N, int K, int k_len, int act)
{
    __shared__ float As[16][132];
    __shared__ float Bs[16][132];
    const int tid  = threadIdx.x;
    const int wave = tid >> 6, lane = tid & 63;
    const int wr = wave >> 1, wc = wave & 1;
    const int ro = wr * 64 + (lane >> 3) * 8;
    const int co = wc * 64 + (lane & 7) * 8;
    const int bm = blockIdx.y * 128, bn = blockIdx.x * 128;
    const int z  = blockIdx.z;
    const int kbeg = z * k_len;
    const int lr = tid >> 2;
    const int kq = (tid & 3) * 4;

    float acc[8][8];
    #pragma unroll
    for (int i = 0; i < 8; ++i)
        #pragma unroll
        for (int j = 0; j < 8; ++j) acc[i][j] = 0.f;

    for (int k0 = kbeg; k0 < kbeg + k_len; k0 += 16) {
        #pragma unroll
        for (int h = 0; h < 2; ++h) {
            int r = lr + h * 64;
            float4 av = make_float4(0.f, 0.f, 0.f, 0.f);
            float4 bv = make_float4(0.f, 0.f, 0.f, 0.f);
            if (bm + r < M) av = *(const float4*)&A[(size_t)(bm + r) * K + k0 + kq];
            if (bn + r < N) bv = *(const float4*)&B[(size_t)(bn + r) * K + k0 + kq];
            As[kq + 0][r] = av.x; As[kq + 1][r] = av.y;
            As[kq + 2][r] = av.z; As[kq + 3][r] = av.w;
            Bs[kq + 0][r] = bv.x; Bs[kq + 1][r] = bv.y;
            Bs[kq + 2][r] = bv.z; Bs[kq + 3][r] = bv.w;
        }
        __syncthreads();
        #pragma unroll
        for (int kk = 0; kk < 16; ++kk) {
            float4 a0 = *(const float4*)&As[kk][ro];
            float4 a1 = *(const float4*)&As[kk][ro + 4];
            float4 b0 = *(const float4*)&Bs[kk][co];
            float4 b1 = *(const float4*)&Bs[kk][co + 4];
            float a[8] = {a0.x, a0.y, a0.z, a0.w, a1.x, a1.y, a1.z, a1.w};
            float b[8] = {b0.x, b0.y, b0.z, b0.w, b1.x, b1.y, b1.z, b1.w};
            #pragma unroll
            for (int i = 0; i < 8; ++i)
                #pragma unroll
                for (int j = 0; j < 8; ++j)
                    acc[i][j] += a[i] * b[j];
        }
        __syncthreads();
    }

    if (Cpart) {
        float* P = Cpart + (size_t)z * M * N;
        #pragma unroll
        for (int i = 0; i < 8; ++i) {
            int row = bm + ro + i;
            #pragma unroll
            for (int jq = 0; jq < 2; ++jq) {
                int col = bn + co + jq * 4;
                if (col < N) {
                    float4 v = make_float4(acc[i][jq * 4 + 0], acc[i][jq * 4 + 1],
                                           acc[i][jq * 4 + 2], acc[i][jq * 4 + 3]);
                    *(float4*)&P[(size_t)row * N + col] = v;
                }
            }
        }
    } else {
        #pragma unroll
        for (int i = 0; i < 8; ++i) {
            int row = bm + ro + i;
            #pragma unroll
            for (int jq = 0; jq < 2; ++jq) {
                int col = bn + co + jq * 4;
                if (col < N) {
                    float4 v = make_float4(acc[i][jq * 4 + 0], acc[i][jq * 4 + 1],
                                           acc[i][jq * 4 + 2], acc[i][jq * 4 + 3]);
                    if (bias) {
                        float4 bv = *(const float4*)&bias[col];
                        v.x += bv.x; v.y += bv.y; v.z += bv.z; v.w += bv.w;
                    }
                    if (act == 1) {
                        v.x = fmaxf(v.x, 0.f); v.y = fmaxf(v.y, 0.f);
                        v.z = fmaxf(v.z, 0.f); v.w = fmaxf(v.w, 0.f);
                    } else if (act == 2) {
                        v.x = 1.f / (1.f + expf(-v.x)); v.y = 1.f / (1.f + expf(-v.y));
                        v.z = 1.f / (1.f + expf(-v.z)); v.w = 1.f / (1.f + expf(-v.w));
                    }
                    *(float4*)&C[(size_t)row * N + col] = v;
                }
            }
        }
    }
}

// ---------------------------------------------------------------------------
// Split-K reduce: C = act( sum_z P[z] + bias ).
// If Chi != nullptr, writes bf16 hi/lo split instead of float C.
// C may alias P's slice 0 (thread i touches only index i).
// ---------------------------------------------------------------------------
__global__ void reduce_slices(const float* __restrict__ P, float* __restrict__ C,
                              short* __restrict__ Chi, short* __restrict__ Clo,
                              const float* __restrict__ bias,
                              int MN, int N, int KS, int act)
{
    int i4 = blockIdx.x * blockDim.x + threadIdx.x;
    size_t base = (size_t)i4 * 4;
    if (base >= (size_t)MN) return;
    float4 s = *(const float4*)&P[base];
    for (int z = 1; z < KS; ++z) {
        float4 v = *(const float4*)&P[(size_t)z * MN + base];
        s.x += v.x; s.y += v.y; s.z += v.z; s.w += v.w;
    }
    if (bias) {
        int col = (int)(base % N);
        float4 bv = *(const float4*)&bias[col];
        s.x += bv.x; s.y += bv.y; s.z += bv.z; s.w += bv.w;
    }
    if (act == 1) {
        s.x = fmaxf(s.x, 0.f); s.y = fmaxf(s.y, 0.f);
        s.z = fmaxf(s.z, 0.f); s.w = fmaxf(s.w, 0.f);
    } else if (act == 2) {
        s.x = 1.f / (1.f + expf(-s.x)); s.y = 1.f / (1.f + expf(-s.y));
        s.z = 1.f / (1.f + expf(-s.z)); s.w = 1.f / (1.f + expf(-s.w));
    }
    if (Chi) {
        float e[4] = {s.x, s.y, s.z, s.w};
        short4 hh, ll;
        hh.x = f2bf(e[0]); ll.x = f2bf(e[0] - bf2f(hh.x));
        hh.y = f2bf(e[1]); ll.y = f2bf(e[1] - bf2f(hh.y));
        hh.z = f2bf(e[2]); ll.z = f2bf(e[2] - bf2f(hh.z));
        hh.w = f2bf(e[3]); ll.w = f2bf(e[3] - bf2f(hh.w));
        *(short4*)&Chi[base] = hh;
        *(short4*)&Clo[base] = ll;
    } else {
        *(float4*)&C[base] = s;
    }
}

// ---------------------------------------------------------------------------
// build_cin: compress-branch input, fused fp32->bf16 hi/lo split.
// ---------------------------------------------------------------------------
__global__ void build_cin(const float* __restrict__ qkv,
                          const float* __restrict__ k_pos,
                          const float* __restrict__ v_pos,
                          short* __restrict__ ckh, short* __restrict__ ckl,
                          short* __restrict__ cvh, short* __restrict__ cvl)
{
    int idx = blockIdx.x * blockDim.x + threadIdx.x;       // KVH*S*DH
    if (idx >= KVH_ * S_ * DH_) return;
    int d = idx & 127;
    int s = (idx >> 7) & 1023;
    int h = idx >> 17;
    int c = s >> 4, t = s & 15;
    float kv = qkv[(size_t)s * QKVN + 4096 + h * DH_ + d];
    float vv = qkv[(size_t)s * QKVN + 5120 + h * DH_ + d];
    size_t row = (size_t)h * NC_ + c;
    size_t col = (size_t)t * DH_ + d;
    float kx = kv + k_pos[(h * 16 + t) * DH_ + d];
    float vx = vv + v_pos[(h * 16 + t) * DH_ + d];
    short kh = f2bf(kx), vh = f2bf(vx);
    ckh[row * CD_ + col] = kh; ckl[row * CD_ + col] = f2bf(kx - bf2f(kh));
    cvh[row * CD_ + col] = vh; cvl[row * CD_ + col] = f2bf(vx - bf2f(vh));
}

// ---------------------------------------------------------------------------
__global__ void assemble_c(const float* __restrict__ ckb, const float* __restrict__ cvb,
                           const float* __restrict__ mem_kv,
                           float* __restrict__ ckf, float* __restrict__ cvf)
{
    int idx = blockIdx.x * blockDim.x + threadIdx.x;       // KVH*65*DH
    if (idx >= KVH_ * 65 * DH_) return;
    int d = idx & 127;
    int j = (idx >> 7) % 65;
    int h = idx / (65 * DH_);
    if (j == 0) {
        ckf[idx] = mem_kv[(0 * KVH_ + h) * DH_ + d];
        cvf[idx] = mem_kv[(1 * KVH_ + h) * DH_ + d];
    } else {
        ckf[idx] = ckb[((size_t)h * NC_ + (j - 1)) * DH_ + d];
        cvf[idx] = cvb[((size_t)h * NC_ + (j - 1)) * DH_ + d];
    }
}

// ---------------------------------------------------------------------------
// Compressed attention, g4-batched: one block per (kvh, s), all 4 grouped
// q-heads share the K/V rows. Fused importance softmax + top-4 selection
// (runs on wave 1 via argmax shuffles) -> csim buffer eliminated.
// ---------------------------------------------------------------------------
__global__ void compress_attn(const float* __restrict__ qkv,
                              const float* __restrict__ ckf,
                              const float* __restrict__ cvf,
                              float* __restrict__ cout,
                              int* __restrict__ selidx, int* __restrict__ fsel)
{
    int b = blockIdx.x;            // h*1024 + s
    int s = b & 1023;
    int h = b >> 10;
    int tid = threadIdx.x;         // 128 = 2 waves
    int wv = tid >> 6;
    __shared__ __align__(16) float qrow[4][128];
    __shared__ float simS[4][65];
    __shared__ float p[4][128];
    __shared__ float redm[2][4], redd[2][4];
    #pragma unroll
    for (int g = 0; g < 4; ++g)
        qrow[g][tid] = qkv[(size_t)s * QKVN + (h * 4 + g) * DH_ + tid];
    __syncthreads();

    float sv[4] = {NEGF, NEGF, NEGF, NEGF};
    if (tid < 65) {
        bool vis = (tid == 0) || (16 * tid - 1 < s);
        if (vis) {
            const float4* kr = (const float4*)(ckf + ((size_t)h * 65 + tid) * DH_);
            float a[4] = {0.f, 0.f, 0.f, 0.f};
            #pragma unroll 4
            for (int d = 0; d < 32; ++d) {
                float4 kq = kr[d];
                #pragma unroll
                for (int g = 0; g < 4; ++g) {
                    float4 qq = *(const float4*)&qrow[g][d * 4];
                    a[g] += kq.x * qq.x + kq.y * qq.y + kq.z * qq.z + kq.w * qq.w;
                }
            }
            #pragma unroll
            for (int g = 0; g < 4; ++g) sv[g] = a[g] * SCALE;
        }
        #pragma unroll
        for (int g = 0; g < 4; ++g) simS[g][tid] = sv[g];
    }

    // wave-parallel softmax x4 (lanes >=65 hold NEGF -> e=0)
    float mg[4];
    #pragma unroll
    for (int g = 0; g < 4; ++g) mg[g] = sv[g];
    #pragma unroll
    for (int off = 32; off; off >>= 1)
        #pragma unroll
        for (int g = 0; g < 4; ++g) mg[g] = fmaxf(mg[g], __shfl_xor(mg[g], off));
    if ((tid & 63) == 0)
        #pragma unroll
        for (int g = 0; g < 4; ++g) redm[wv][g] = mg[g];
    __syncthreads();                    // also publishes simS
    float e[4];
    #pragma unroll
    for (int g = 0; g < 4; ++g) {
        float m = fmaxf(redm[0][g], redm[1][g]);
        e[g] = (tid < 65) ? expf(sv[g] - m) : 0.f;
        p[g][tid] = e[g];
    }
    __syncthreads();
    #pragma unroll
    for (int off = 32; off; off >>= 1)
        #pragma unroll
        for (int g = 0; g < 4; ++g) e[g] += __shfl_xor(e[g], off);
    if ((tid & 63) == 0)
        #pragma unroll
        for (int g = 0; g < 4; ++g) redd[wv][g] = e[g];
    __syncthreads();
    float inv[4];
    #pragma unroll
    for (int g = 0; g < 4; ++g) inv[g] = 1.f / (redd[0][g] + redd[1][g]);

    // importance + top-4 on wave 1 (lane j = key j+1); wave 0 goes to PV
    if (wv == 1) {
        int j = tid - 64;
        float v = 0.25f * (simS[0][j + 1] + simS[1][j + 1] +
                           simS[2][j + 1] + simS[3][j + 1]);
        float m2 = v;
        #pragma unroll
        for (int off = 32; off; off >>= 1) m2 = fmaxf(m2, __shfl_xor(m2, off));
        m2 = fmaxf(m2, -1e3f);
        float e2 = expf(v - m2);
        float den2 = e2;
        #pragma unroll
        for (int off = 32; off; off >>= 1) den2 += __shfl_xor(den2, off);
        den2 += expf(-1e3f - m2);
        float pv = e2 / den2;           // lane j holds prob of block j
        size_t base5 = ((size_t)h * S_ + s) * 5;
        size_t base4 = ((size_t)h * S_ + s) * 4;
        float cv = pv; int ci = j;
        for (int t = 0; t < 4; ++t) {
            float bv = cv; int bi = ci;
            #pragma unroll
            for (int off = 32; off; off >>= 1) {
                float ov = __shfl_xor(bv, off);
                int   oi = __shfl_xor(bi, off);
                if (ov > bv || (ov == bv && oi < bi)) { bv = ov; bi = oi; }
            }
            if (j == 0) {
                selidx[base5 + t] = bi;
                fsel[base4 + t]   = (bv > 1e-10f) ? 1 : 0;
            }
            if (ci == bi) cv = -1.f;    // remove winner
        }
        if (j == 0) selidx[base5 + 4] = s >> 4;
    }

    // PV: thread owns output dim d=tid for all 4 g
    float acc[4] = {0.f, 0.f, 0.f, 0.f};
    const float* vbase = cvf + (size_t)h * 65 * DH_ + tid;
    #pragma unroll 4
    for (int j = 0; j < 65; ++j) {
        float v = vbase[(size_t)j * DH_];
        #pragma unroll
        for (int g = 0; g < 4; ++g) acc[g] += p[g][j] * v;
    }
    #pragma unroll
    for (int g = 0; g < 4; ++g)
        cout[(size_t)s * 4096 + (h * 4 + g) * DH_ + tid] = acc[g] * inv[g];
}

// ---------------------------------------------------------------------------
__global__ void rope_inplace(float* __restrict__ qkv)
{
    int idx = blockIdx.x * blockDim.x + threadIdx.x;
    const int totq = S_ * H_ * 64;
    const int totk = S_ * KVH_ * 64;
    float* base;
    int p, s;
    if (idx < totq) {
        p = idx & 63; int head = (idx >> 6) & 31; s = idx >> 11;
        base = qkv + (size_t)s * QKVN + head * DH_;
    } else {
        int i2 = idx - totq;
        if (i2 >= totk) return;
        p = i2 & 63; int head = (i2 >> 6) & 7; s = i2 >> 9;
        base = qkv + (size_t)s * QKVN + 4096 + head * DH_;
    }
    // 10000^(-2p/128) = exp2(-p * log2(10000)/64)
    float inv = exp2f(-0.2076205060833595f * (float)p);
    float ang = (float)s * inv;
    float c = cosf(ang), sn = sinf(ang);
    float x0 = base[2 * p], x1 = base[2 * p + 1];
    base[2 * p]     = x0 * c - x1 * sn;
    base[2 * p + 1] = x1 * c + x0 * sn;
}

// ---------------------------------------------------------------------------
// Fine (selected-block) attention, g4-batched: one block per (kvh, s).
// 80 keys = 4 selected blocks + own block; 4 q-heads share K/V rows.
// ---------------------------------------------------------------------------
__global__ void fine_attn(const float* __restrict__ qkv,
                          const int* __restrict__ selidx, const int* __restrict__ fsel,
                          float* __restrict__ fout)
{
    int b = blockIdx.x;        // h*1024 + s
    int s = b & 1023;
    int h = b >> 10;
    int tid = threadIdx.x;     // 128 = 2 waves
    int wv = tid >> 6;
    __shared__ __align__(16) float qrow[4][128];
    __shared__ float p[4][128];
    __shared__ int   blk[5];
    __shared__ int   bvis[5];
    __shared__ float redm[2][4], redd[2][4];
    if (tid < 5) {
        blk[tid]  = selidx[((size_t)h * S_ + s) * 5 + tid];
        bvis[tid] = (tid < 4) ? fsel[((size_t)h * S_ + s) * 4 + tid] : 1;
    }
    #pragma unroll
    for (int g = 0; g < 4; ++g)
        qrow[g][tid] = qkv[(size_t)s * QKVN + (h * 4 + g) * DH_ + tid];
    __syncthreads();

    float sv[4] = {NEGF, NEGF, NEGF, NEGF};
    if (tid < 80) {
        int bi = tid >> 4, t = tid & 15;
        int pos = blk[bi] * 16 + t;
        bool vis = (bi < 4) ? (bvis[bi] != 0) : (t <= (s & 15));
        if (vis) {
            const float4* kr = (const float4*)(qkv + (size_t)pos * QKVN + 4096 + h * DH_);
            float a[4] = {0.f, 0.f, 0.f, 0.f};
            #pragma unroll 4
            for (int d = 0; d < 32; ++d) {
                float4 kq = kr[d];
                #pragma unroll
                for (int g = 0; g < 4; ++g) {
                    float4 qq = *(const float4*)&qrow[g][d * 4];
                    a[g] += kq.x * qq.x + kq.y * qq.y + kq.z * qq.z + kq.w * qq.w;
                }
            }
            #pragma unroll
            for (int g = 0; g < 4; ++g) sv[g] = a[g] * SCALE;
        }
    }

    float mg[4];
    #pragma unroll
    for (int g = 0; g < 4; ++g) mg[g] = sv[g];
    #pragma unroll
    for (int off = 32; off; off >>= 1)
        #pragma unroll
        for (int g = 0; g < 4; ++g) mg[g] = fmaxf(mg[g], __shfl_xor(mg[g], off));
    if ((tid & 63) == 0)
        #pragma unroll
        for (int g = 0; g < 4; ++g) redm[wv][g] = mg[g];
    __syncthreads();
    float e[4];
    #pragma unroll
    for (int g = 0; g < 4; ++g) {
        float m = fmaxf(redm[0][g], redm[1][g]);
        e[g] = (tid < 80) ? expf(sv[g] - m) : 0.f;
        p[g][tid] = e[g];
    }
    __syncthreads();
    #pragma unroll
    for (int off = 32; off; off >>= 1)
        #pragma unroll
        for (int g = 0; g < 4; ++g) e[g] += __shfl_xor(e[g], off);
    if ((tid & 63) == 0)
        #pragma unroll
        for (int g = 0; g < 4; ++g) redd[wv][g] = e[g];
    __syncthreads();
    float inv[4];
    #pragma unroll
    for (int g = 0; g < 4; ++g) inv[g] = 1.f / (redd[0][g] + redd[1][g]);

    float acc[4] = {0.f, 0.f, 0.f, 0.f};
    const float* vbase = qkv + 5120 + h * DH_ + tid;
    #pragma unroll
    for (int bi = 0; bi < 5; ++bi) {
        const float* vb = vbase + (size_t)(blk[bi] * 16) * QKVN;
        #pragma unroll 4
        for (int t = 0; t < 16; ++t) {
            float v = vb[(size_t)t * QKVN];
            #pragma unroll
            for (int g = 0; g < 4; ++g) acc[g] += p[g][bi * 16 + t] * v;
        }
    }
    #pragma unroll
    for (int g = 0; g < 4; ++g)
        fout[(size_t)s * 4096 + (h * 4 + g) * DH_ + tid] = acc[g] * inv[g];
}

// ---------------------------------------------------------------------------
// Sliding-window attention, g4-batched: one block per (kvh, s); 65 keys.
// ---------------------------------------------------------------------------
__global__ void sliding_attn(const float* __restrict__ qkv, float* __restrict__ sout)
{
    int b = blockIdx.x;        // kvh*1024 + s
    int s = b & 1023;
    int h = b >> 10;           // kvh
    int tid = threadIdx.x;     // 128 = 2 waves
    int wv = tid >> 6;
    __shared__ __align__(16) float qrow[4][128];
    __shared__ float p[4][128];
    __shared__ float redm[2][4], redd[2][4];
    #pragma unroll
    for (int g = 0; g < 4; ++g)
        qrow[g][tid] = qkv[(size_t)s * QKVN + (h * 4 + g) * DH_ + tid];
    __syncthreads();

    float sv[4] = {NEGF, NEGF, NEGF, NEGF};
    if (tid < 65) {
        int pos = s - tid;
        if (pos >= 0) {
            const float4* kr = (const float4*)(qkv + (size_t)pos * QKVN + 4096 + h * DH_);
            float a[4] = {0.f, 0.f, 0.f, 0.f};
            #pragma unroll 4
            for (int d = 0; d < 32; ++d) {
                float4 kq = kr[d];
                #pragma unroll
                for (int g = 0; g < 4; ++g) {
                    float4 qq = *(const float4*)&qrow[g][d * 4];
                    a[g] += kq.x * qq.x + kq.y * qq.y + kq.z * qq.z + kq.w * qq.w;
                }
            }
            #pragma unroll
            for (int g = 0; g < 4; ++g) sv[g] = a[g] * SCALE;
        }
    }

    float mg[4];
    #pragma unroll
    for (int g = 0; g < 4; ++g) mg[g] = sv[g];
    #pragma unroll
    for (int off = 32; off; off >>= 1)
        #pragma unroll
        for (int g = 0; g < 4; ++g) mg[g] = fmaxf(mg[g], __shfl_xor(mg[g], off));
    if ((tid & 63) == 0)
        #pragma unroll
        for (int g = 0; g < 4; ++g) redm[wv][g] = mg[g];
    __syncthreads();
    float e[4];
    #pragma unroll
    for (int g = 0; g < 4; ++g) {
        float m = fmaxf(redm[0][g], redm[1][g]);
        e[g] = (tid < 65) ? expf(sv[g] - m) : 0.f;
        p[g][tid] = e[g];
    }
    __syncthreads();
    #pragma unroll
    for (int off = 32; off; off >>= 1)
        #pragma unroll
        for (int g = 0; g < 4; ++g) e[g] += __shfl_xor(e[g], off);
    if ((tid & 63) == 0)
        #pragma unroll
        for (int g = 0; g < 4; ++g) redd[wv][g] = e[g];
    __syncthreads();
    float inv[4];
    #pragma unroll
    for (int g = 0; g < 4; ++g) inv[g] = 1.f / (redd[0][g] + redd[1][g]);

    float acc[4] = {0.f, 0.f, 0.f, 0.f};
    int lim = (s + 1 < 65) ? (s + 1) : 65;
    const float* vbase = qkv + (size_t)s * QKVN + 5120 + h * DH_ + tid;
    #pragma unroll 4
    for (int j = 0; j < lim; ++j) {
        float v = *(vbase - (size_t)j * QKVN);
        #pragma unroll
        for (int g = 0; g < 4; ++g) acc[g] += p[g][j] * v;
    }
    #pragma unroll
    for (int g = 0; g < 4; ++g)
        sout[(size_t)s * 4096 + (h * 4 + g) * DH_ + tid] = acc[g] * inv[g];
}

// ---------------------------------------------------------------------------
// combine_gate: gated 3-way sum, fused fp32->bf16 hi/lo split for out-proj A.
// ---------------------------------------------------------------------------
__global__ void combine_gate(const float* __restrict__ cout, const float* __restrict__ fout,
                             const float* __restrict__ sout, const float* __restrict__ gates,
                             short* __restrict__ oh, short* __restrict__ ol)
{
    int idx = blockIdx.x * blockDim.x + threadIdx.x;   // S*4096
    if (idx >= S_ * 4096) return;
    int h = (idx >> 7) & 31;
    int s = idx >> 12;
    float g0 = gates[(size_t)s * 96 + h * 3 + 0];
    float g1 = gates[(size_t)s * 96 + h * 3 + 1];
    float g2 = gates[(size_t)s * 96 + h * 3 + 2];
    float v = g0 * cout[idx] + g1 * fout[idx] + g2 * sout[idx];
    short hv = f2bf(v);
    oh[idx] = hv;
    ol[idx] = f2bf(v - bf2f(hv));
}

// ---------------------------------------------------------------------------
extern "C" void kernel_launch(void* const* d_in, const int* in_sizes, int n_in,
                              void* d_out, int out_size, void* d_ws, size_t ws_size,
                              hipStream_t stream)
{
    const float* hidden = (const float*)d_in[0];
    const float* w_qkv  = (const float*)d_in[1];
    const float* w_o    = (const float*)d_in[2];
    const float* k_pos  = (const float*)d_in[3];
    const float* v_pos  = (const float*)d_in[4];
    const float* k_w1   = (const float*)d_in[5];
    const float* k_b1   = (const float*)d_in[6];
    const float* k_w2   = (const float*)d_in[7];
    const float* k_b2   = (const float*)d_in[8];
    const float* v_w1   = (const float*)d_in[9];
    const float* v_b1   = (const float*)d_in[10];
    const float* v_w2   = (const float*)d_in[11];
    const float* v_b2   = (const float*)d_in[12];
    const float* mem_kv = (const float*)d_in[13];
    const float* w_gate = (const float*)d_in[14];
    const float* b_gate = (const float*)d_in[15];
    float* out = (float*)d_out;

    float* ws = (float*)d_ws;
    size_t o = 0;
    float* qkv    = ws + o; o += (size_t)S_ * QKVN;
    short* ckin_h = (short*)(ws + o); o += (size_t)512 * CD_ / 2;
    short* ckin_l = (short*)(ws + o); o += (size_t)512 * CD_ / 2;
    short* cvin_h = (short*)(ws + o); o += (size_t)512 * CD_ / 2;
    short* cvin_l = (short*)(ws + o); o += (size_t)512 * CD_ / 2;
    short* h1h    = (short*)(ws + o); o += (size_t)512 * CD_ / 2;
    short* h1l    = (short*)(ws + o); o += (size_t)512 * CD_ / 2;
    float* ckb    = ws + o; o += (size_t)512 * DH_;
    float* cvb    = ws + o; o += (size_t)512 * DH_;
    float* ckf    = ws + o; o += (size_t)KVH_ * 65 * DH_;
    float* cvf    = ws + o; o += (size_t)KVH_ * 65 * DH_;
    float* coutb  = ws + o; o += (size_t)S_ * 4096;
    float* foutb  = ws + o; o += (size_t)S_ * 4096;   // } triple doubles as
    float* soutb  = ws + o; o += (size_t)S_ * 4096;   // } split-K partials
    float* gatesb = ws + o; o += (size_t)S_ * 96;
    int*   selidx = (int*)(ws + o); o += (size_t)KVH_ * S_ * 5;
    int*   fsel   = (int*)(ws + o); o += (size_t)KVH_ * S_ * 4;
    short* hid_h  = (short*)(ws + o); o += (size_t)S_ * 4096 / 2;
    short* hid_l  = (short*)(ws + o); o += (size_t)S_ * 4096 / 2;
    short* cmb_h  = (short*)(ws + o); o += (size_t)S_ * 4096 / 2;
    short* cmb_l  = (short*)(ws + o); o += (size_t)S_ * 4096 / 2;
    // shared weight-split scratch, sized for w_qkv (largest); reused
    // sequentially (stream-ordered): w_qkv, k_w1, k_w2, v_w1, v_w2, w_o.
    short* wsp_h  = (short*)(ws + o); o += (size_t)QKVN * 4096 / 2;
    short* wsp_l  = (short*)(ws + o); o += (size_t)QKVN * 4096 / 2;

    // Split-K partial buffers (stream-ordered dead aliases):
    //  - qkv z=2 (12.58M floats): Pq = coutb..soutb span (exact fit; dead
    //    until compress_attn, qkv reduce completes before it).
    //  - gates/MLP1 (<=8.39M): P = foutb..soutb span (dead until step 12).
    //  - out-proj z=4 (16.78M): Po = ws+0 span (qkv..coutb all dead after
    //    combine_gate; hid/cmb/wsp live and lie beyond the span's end?
    //    span covers qkv(6.29M)+ckin/cvin(4.19M)+h1(2.10M)+ckb/cvb(0.13M)+
    //    ckf/cvf(0.13M)+coutb(4.19M) = 17.04M >= 16.78M; foutb onward
    //    untouched).
    float* Pq = coutb;
    float* P  = foutb;
    float* Po = ws;

    // 0. pre-split activations/weights to bf16 hi/lo
    {
        long n = (long)S_ * 4096;
        split_pair<<<(int)((n / 8 + 255) / 256), 256, 0, stream>>>(hidden, hid_h, hid_l, n);
        long nw = (long)QKVN * 4096;
        split_pair<<<(int)((nw / 8 + 255) / 256), 256, 0, stream>>>(w_qkv, wsp_h, wsp_l, nw);
    }

    // 1. qkv projection [1024,6144] — bf3 split-K=2 (768 blocks, 3/CU;
    //    measured best: 238us)
    gemm_bf3<<<dim3(QKVN / 128, S_ / 128, 2), 256, 0, stream>>>(
        hid_h, hid_l, wsp_h, wsp_l, nullptr, Pq, nullptr,
        S_, QKVN, 4096, QKVN, 2048, 0);
    reduce_slices<<<(S_ * QKVN / 4 + 255) / 256, 256, 0, stream>>>(
        Pq, qkv, nullptr, nullptr, nullptr, S_ * QKVN, QKVN, 2, 0);

    // 2. gates [1024,96] — vector split-K=16 (N not a multiple of 128)
    gemm128<<<dim3(1, S_ / 128, 16), 256, 0, stream>>>(
        hidden, w_gate, nullptr, P, nullptr, S_, 96, 4096, 256, 0);
    reduce_slices<<<(S_ * 96 / 4 + 255) / 256, 256, 0, stream>>>(
        P, gatesb, nullptr, nullptr, b_gate, S_ * 96, 96, 16, 2);

    // 3. compress inputs (fused split)
    build_cin<<<(KVH_ * S_ * DH_ + 255) / 256, 256, 0, stream>>>(
        qkv, k_pos, v_pos, ckin_h, ckin_l, cvin_h, cvin_l);

    // 4-7. compress MLPs. MLP1: bf3 z=8 (512 blocks), reduce fuses
    //      relu + hi/lo split. MLP2: w64 z=32 (512 blocks), reduce + bias.
    {
        long nw = (long)CD_ * CD_;
        split_pair<<<(int)((nw / 8 + 255) / 256), 256, 0, stream>>>(k_w1, wsp_h, wsp_l, nw);
    }
    gemm_bf3<<<dim3(CD_ / 128, 4, 8), 256, 0, stream>>>(
        ckin_h, ckin_l, wsp_h, wsp_l, nullptr, P, nullptr,
        512, CD_, CD_, CD_, 256, 0);
    reduce_slices<<<(512 * CD_ / 4 + 255) / 256, 256, 0, stream>>>(
        P, nullptr, h1h, h1l, k_b1, 512 * CD_, CD_, 8, 1);
    {
        long nw = (long)DH_ * CD_;
        split_pair<<<(int)((nw / 8 + 255) / 256), 256, 0, stream>>>(k_w2, wsp_h, wsp_l, nw);
    }
    gemm_w64<<<dim3(DH_ / 64, 8, 32), 64, 0, stream>>>(
        h1h, h1l, wsp_h, wsp_l, nullptr, P, nullptr,
        512, DH_, CD_, DH_, 64, 0);
    reduce_slices<<<(512 * DH_ / 4 + 255) / 256, 256, 0, stream>>>(
        P, ckb, nullptr, nullptr, k_b2, 512 * DH_, DH_, 32, 0);

    {
        long nw = (long)CD_ * CD_;
        split_pair<<<(int)((nw / 8 + 255) / 256), 256, 0, stream>>>(v_w1, wsp_h, wsp_l, nw);
    }
    gemm_bf3<<<dim3(CD_ / 128, 4, 8), 256, 0, stream>>>(
        cvin_h, cvin_l, wsp_h, wsp_l, nullptr, P, nullptr,
        512, CD_, CD_, CD_, 256, 0);
    reduce_slices<<<(512 * CD_ / 4 + 255) / 256, 256, 0, stream>>>(
        P, nullptr, h1h, h1l, v_b1, 512 * CD_, CD_, 8, 1);
    {
        long nw = (long)DH_ * CD_;
        split_pair<<<(int)((nw / 8 + 255) / 256), 256, 0, stream>>>(v_w2, wsp_h, wsp_l, nw);
    }
    gemm_w64<<<dim3(DH_ / 64, 8, 32), 64, 0, stream>>>(
        h1h, h1l, wsp_h, wsp_l, nullptr, P, nullptr,
        512, DH_, CD_, DH_, 64, 0);
    reduce_slices<<<(512 * DH_ / 4 + 255) / 256, 256, 0, stream>>>(
        P, cvb, nullptr, nullptr, v_b2, 512 * DH_, DH_, 32, 0);

    // 8. prepend mem token
    assemble_c<<<(KVH_ * 65 * DH_ + 255) / 256, 256, 0, stream>>>(ckb, cvb, mem_kv, ckf, cvf);

    // 9+10. compressed attention, g4-batched + fused importance/top-k
    compress_attn<<<KVH_ * S_, 128, 0, stream>>>(qkv, ckf, cvf, coutb, selidx, fsel);

    // 11. RoPE in place on q and k slices of qkv
    {
        int tot = S_ * H_ * 64 + S_ * KVH_ * 64;
        rope_inplace<<<(tot + 255) / 256, 256, 0, stream>>>(qkv);
    }

    // 12. fine (selected-block) attention, g4-batched
    fine_attn<<<KVH_ * S_, 128, 0, stream>>>(qkv, selidx, fsel, foutb);

    // 13. sliding-window attention, g4-batched
    sliding_attn<<<KVH_ * S_, 128, 0, stream>>>(qkv, soutb);

    // 14. gated combine -> bf16 hi/lo (out-proj A operand)
    combine_gate<<<(S_ * 4096 + 255) / 256, 256, 0, stream>>>(
        coutb, foutb, soutb, gatesb, cmb_h, cmb_l);

    // 15. output projection [1024,4096] — bf3 split-K=4 (1024 blocks, 4/CU)
    {
        long nw = (long)4096 * 4096;
        split_pair<<<(int)((nw / 8 + 255) / 256), 256, 0, stream>>>(w_o, wsp_h, wsp_l, nw);
    }
    gemm_bf3<<<dim3(4096 / 128, S_ / 128, 4), 256, 0, stream>>>(
        cmb_h, cmb_l, wsp_h, wsp_l, nullptr, Po, nullptr,
        S_, 4096, 4096, 4096, 1024, 0);
    reduce_slices<<<(S_ * 4096 / 4 + 255) / 256, 256, 0, stream>>>(
        Po, out, nullptr, nullptr, nullptr, S_ * 4096, 4096, 4, 0);
}